// Round 3
// baseline (67.787 us; speedup 1.0000x reference)
//
#include <hip/hip_runtime.h>

// out[b, n*7+c, w] = sum_k x[b, w*3+k-21, c] * kern[n, k]   (n in 0..72)
// out[b, 511,   w] = sum_k x[b, w*3+k-21, 0] * kern[73, k]
// Output (32, 512, 2736) fp32.  Strategy: transpose x to xT[b][c][s+21]
// (contiguous windows), then write-streaming main kernel: each thread owns a
// float4 of 4 consecutive w for 4 consecutive n-rows -> sequential 2.7KB row
// bursts per block, nontemporal stores.

typedef float f32x4 __attribute__((ext_vector_type(4)));   // native vec for nontemporal builtins

constexpr int Bn   = 32;
constexpr int Sn   = 8192;
constexpr int Cn   = 7;
constexpr int Kn   = 8;
constexpr int PADn = 21;
constexpr int Wn   = 2736;           // (8192+21-8)/3 + 1
constexpr int OCH  = 512;            // 73*7 + 1
constexpr int W4   = Wn / 4;         // 684 float4 chunks per row
constexpr int WQ   = W4 / 4;         // 171 chunks per w-quarter (exact)
constexpr int XSTR = 8224;           // padded xT row stride (floats), 32B-mult
constexpr size_t XT_BYTES = (size_t)Bn * Cn * XSTR * 4;   // ~7.37 MB

// ---------------- stage 1: transpose + pad ----------------
__global__ __launch_bounds__(256)
void transpose_pad(const float* __restrict__ x, float* __restrict__ xT) {
    int idx = blockIdx.x * 256 + threadIdx.x;
    const int total = Bn * Cn * XSTR;
    if (idx >= total) return;
    int s2  = idx % XSTR;
    int rem = idx / XSTR;
    int c   = rem % Cn;
    int b   = rem / Cn;
    int s   = s2 - PADn;
    float v = 0.0f;
    if (s >= 0 && s < Sn) v = x[((size_t)b * Sn + s) * Cn + c];
    xT[idx] = v;          // coalesced writes along s2
}

// ---------------- stage 2: main conv, sequential write streaming ----------
// grid (4, 19, 32) = (w-quarter, n-group, batch); 256 threads.
// g<18: rows n = 4g..4g+3 (x-window reused 4x). g==18: n=72 plus final row 511.
__global__ __launch_bounds__(256)
void conv_main(const float* __restrict__ xT, const float* __restrict__ kern,
               float* __restrict__ out) {
    const int tid = threadIdx.x;
    const int wq  = blockIdx.x;          // 0..3
    const int g   = blockIdx.y;          // 0..18
    const int b   = blockIdx.z;          // 0..31
    const int n0  = 4 * g;
    const bool last = (g == 18);

    // wave-uniform weight loads (scalar path)
    float kw[4][8];
#pragma unroll
    for (int j = 0; j < 4; ++j) {
        if (j == 0 || !last) {
            const float* kr = kern + (n0 + j) * Kn;
#pragma unroll
            for (int k = 0; k < 8; ++k) kw[j][k] = kr[k];
        }
    }
    float kfin[8];
    if (last) {
#pragma unroll
        for (int k = 0; k < 8; ++k) kfin[k] = kern[73 * Kn + k];
    }

    const float* xb = xT + (size_t)b * Cn * XSTR;
    float* ob       = out + (size_t)b * OCH * Wn;

    for (int s = tid; s < Cn * WQ; s += 256) {
        int c   = s / WQ;
        int w4  = wq * WQ + (s - c * WQ);
        const float* xr = xb + c * XSTR + 12 * w4;   // 16B-aligned

        float xw[17];
        *reinterpret_cast<f32x4*>(xw + 0)  = *reinterpret_cast<const f32x4*>(xr + 0);
        *reinterpret_cast<f32x4*>(xw + 4)  = *reinterpret_cast<const f32x4*>(xr + 4);
        *reinterpret_cast<f32x4*>(xw + 8)  = *reinterpret_cast<const f32x4*>(xr + 8);
        *reinterpret_cast<f32x4*>(xw + 12) = *reinterpret_cast<const f32x4*>(xr + 12);
        xw[16] = xr[16];

#pragma unroll
        for (int j = 0; j < 4; ++j) {
            if (j == 0 || !last) {
                float a0 = 0.f, a1 = 0.f, a2 = 0.f, a3 = 0.f;
#pragma unroll
                for (int k = 0; k < 8; ++k) {
                    a0 = fmaf(xw[0 + k], kw[j][k], a0);
                    a1 = fmaf(xw[3 + k], kw[j][k], a1);
                    a2 = fmaf(xw[6 + k], kw[j][k], a2);
                    a3 = fmaf(xw[9 + k], kw[j][k], a3);
                }
                f32x4 o = {a0, a1, a2, a3};
                f32x4* dst = reinterpret_cast<f32x4*>(
                    ob + (size_t)((n0 + j) * 7 + c) * Wn + 4 * w4);
                __builtin_nontemporal_store(o, dst);
            }
        }
        if (last && c == 0) {
            float a0 = 0.f, a1 = 0.f, a2 = 0.f, a3 = 0.f;
#pragma unroll
            for (int k = 0; k < 8; ++k) {
                a0 = fmaf(xw[0 + k], kfin[k], a0);
                a1 = fmaf(xw[3 + k], kfin[k], a1);
                a2 = fmaf(xw[6 + k], kfin[k], a2);
                a3 = fmaf(xw[9 + k], kfin[k], a3);
            }
            f32x4 o = {a0, a1, a2, a3};
            f32x4* dst = reinterpret_cast<f32x4*>(
                ob + (size_t)511 * Wn + 4 * w4);
            __builtin_nontemporal_store(o, dst);
        }
    }
}

// ---------------- fallback (round-1 kernel, used only if ws too small) -----
constexpr int WTILE  = 256;
constexpr int NGROUP = 4;
constexpr int NSAMP  = (WTILE - 1) * 3 + Kn;
constexpr int XTILE  = NSAMP * Cn;

__global__ __launch_bounds__(256)
void strided_conv_fallback(const float* __restrict__ x,
                           const float* __restrict__ kern,
                           float* __restrict__ out) {
    __shared__ float lx[XTILE];
    __shared__ float lk[74 * Kn];
    const int tid = threadIdx.x;
    const int w0  = blockIdx.x * WTILE;
    const int b   = blockIdx.y;
    const int g   = blockIdx.z;
    const int sbase7 = (w0 * 3 - PADn) * Cn;
    const float* xb = x + (size_t)b * (Sn * Cn);
    for (int i = tid; i < XTILE; i += 256) {
        int off = sbase7 + i;
        lx[i] = (off >= 0 && off < Sn * Cn) ? xb[off] : 0.0f;
    }
    for (int i = tid; i < 74 * Kn; i += 256) lk[i] = kern[i];
    __syncthreads();
    const int w = w0 + tid;
    if (w >= Wn) return;
    float win[Cn][Kn];
#pragma unroll
    for (int k = 0; k < Kn; ++k) {
        const int base = (tid * 3 + k) * Cn;
#pragma unroll
        for (int c = 0; c < Cn; ++c) win[c][k] = lx[base + c];
    }
    const int n0 = (73 * g) / NGROUP;
    const int n1 = (73 * (g + 1)) / NGROUP;
    float* ob = out + (size_t)b * OCH * Wn + w;
    for (int n = n0; n < n1; ++n) {
        float kn[Kn];
#pragma unroll
        for (int k = 0; k < Kn; ++k) kn[k] = lk[n * Kn + k];
#pragma unroll
        for (int c = 0; c < Cn; ++c) {
            float acc = 0.0f;
#pragma unroll
            for (int k = 0; k < Kn; ++k) acc = fmaf(win[c][k], kn[k], acc);
            ob[(size_t)(n * 7 + c) * Wn] = acc;
        }
    }
    if (g == NGROUP - 1) {
        float acc = 0.0f;
#pragma unroll
        for (int k = 0; k < Kn; ++k) acc = fmaf(win[0][k], lk[73 * Kn + k], acc);
        ob[(size_t)511 * Wn] = acc;
    }
}

extern "C" void kernel_launch(void* const* d_in, const int* in_sizes, int n_in,
                              void* d_out, int out_size, void* d_ws, size_t ws_size,
                              hipStream_t stream) {
    const float* x    = (const float*)d_in[0];
    const float* kern = (const float*)d_in[1];
    float* out        = (float*)d_out;

    if (ws_size >= XT_BYTES) {
        float* xT = (float*)d_ws;
        const int total = Bn * Cn * XSTR;
        transpose_pad<<<(total + 255) / 256, 256, 0, stream>>>(x, xT);
        conv_main<<<dim3(4, 19, 32), 256, 0, stream>>>(xT, kern, out);
    } else {
        strided_conv_fallback<<<dim3((Wn + WTILE - 1) / WTILE, Bn, NGROUP),
                                256, 0, stream>>>(x, kern, out);
    }
}

// Round 4
// 40.434 us; speedup vs baseline: 1.6765x; 1.6765x over previous
//
#include <hip/hip_runtime.h>

// out[b, n*7+c, w] = sum_k x[b, w*3+k-21, c] * kern[n, k]   (n in 0..72)
// out[b, 511,   w] = sum_k x[b, w*3+k-21, 0] * kern[73, k]
// Output (32, 512, 2736) fp32.
//
// Single kernel, round-1 structure, ONE change: float4 output chunks.
// Lane owns 4 consecutive w (one 16B chunk); wave = 64 lanes = 1KB
// contiguous per store instruction. Waves are row-uniform. x tile staged
// in LDS with a 13-per-12 padded per-channel layout so the stride-12
// window reads are bank-conflict-free (13 coprime 32).

typedef float f32x4 __attribute__((ext_vector_type(4)));

constexpr int Bn   = 32;
constexpr int Sn   = 8192;
constexpr int Cn   = 7;
constexpr int Kn   = 8;
constexpr int PADn = 21;
constexpr int Wn   = 2736;          // (8192+21-8)/3 + 1
constexpr int OCH  = 512;           // 73*7 + 1
constexpr int NCH  = 684;           // float4 chunks per row (2736/4)
constexpr int CHT  = 64;            // chunks per block (256 w)
constexpr int NWQ  = 11;            // ceil(684/64)
constexpr int SAMP = 773;           // samples per tile: (256-1)*3 + 8
constexpr int CSTR = 840;           // padded per-channel LDS stride (max idx 836)

__global__ __launch_bounds__(256)
void conv_v4(const float* __restrict__ x, const float* __restrict__ kern,
             float* __restrict__ out) {
    __shared__ float lx[Cn * CSTR];      // 23.5 KB -> 6 blocks/CU

    const int tid = threadIdx.x;
    const int wq  = blockIdx.x;          // 0..10  (w-tile)
    const int g   = blockIdx.y;          // 0..3   (n-group)
    const int b   = blockIdx.z;          // 0..31

    // ---- stage: dense global region -> padded per-channel LDS rows ----
    // sample s (local), channel c lives at lx[c*CSTR + s + s/12]
    const int sbase = wq * 768 - PADn;           // first sample (may be < 0)
    const int g0    = sbase * Cn;                // flat float offset in batch
    const float* xb = x + (size_t)b * Sn * Cn;
    for (int i = tid; i < SAMP * Cn; i += 256) {
        int gg = g0 + i;
        float v = (gg >= 0 && gg < Sn * Cn) ? xb[gg] : 0.0f;   // dense, coalesced
        int s = i / 7;
        int c = i - 7 * s;
        lx[c * CSTR + s + s / 12] = v;
    }
    __syncthreads();

    const int lane  = tid & 63;
    const int r     = __builtin_amdgcn_readfirstlane(tid >> 6);  // wave id 0..3
    const int chunk = wq * CHT + lane;
    if (chunk >= NCH) return;            // only wq==10, lanes 44..63

    const int n0 = (73 * g) / 4;
    const int n1 = (73 * (g + 1)) / 4;
    float* ob = out + (size_t)b * OCH * Wn + 4 * chunk;
    const int base = 13 * lane;          // padded addr of sample 12*lane

    for (int c = 0; c < Cn; ++c) {
        // window: 17 samples starting at s=12*lane -> padded base 13*lane
        float xw[17];
        const float* lr = lx + c * CSTR + base;
#pragma unroll
        for (int j = 0; j < 17; ++j) xw[j] = lr[j + (j >= 12 ? 1 : 0)];

        for (int n = n0 + r; n < n1; n += 4) {   // wave-uniform rows
            const float* kr = kern + n * Kn;
            float a0 = 0.f, a1 = 0.f, a2 = 0.f, a3 = 0.f;
#pragma unroll
            for (int k = 0; k < 8; ++k) {
                float kv = kr[k];
                a0 = fmaf(xw[0 + k], kv, a0);
                a1 = fmaf(xw[3 + k], kv, a1);
                a2 = fmaf(xw[6 + k], kv, a2);
                a3 = fmaf(xw[9 + k], kv, a3);
            }
            f32x4 o = {a0, a1, a2, a3};
            *reinterpret_cast<f32x4*>(ob + (size_t)(n * 7 + c) * Wn) = o;
        }
        if (c == 0 && g == 3 && r == 3) {        // final row 511 (kern 73, ch 0)
            const float* kr = kern + 73 * Kn;
            float a0 = 0.f, a1 = 0.f, a2 = 0.f, a3 = 0.f;
#pragma unroll
            for (int k = 0; k < 8; ++k) {
                float kv = kr[k];
                a0 = fmaf(xw[0 + k], kv, a0);
                a1 = fmaf(xw[3 + k], kv, a1);
                a2 = fmaf(xw[6 + k], kv, a2);
                a3 = fmaf(xw[9 + k], kv, a3);
            }
            f32x4 o = {a0, a1, a2, a3};
            *reinterpret_cast<f32x4*>(ob + (size_t)511 * Wn) = o;
        }
    }
}

extern "C" void kernel_launch(void* const* d_in, const int* in_sizes, int n_in,
                              void* d_out, int out_size, void* d_ws, size_t ws_size,
                              hipStream_t stream) {
    const float* x    = (const float*)d_in[0];
    const float* kern = (const float*)d_in[1];
    float* out        = (float*)d_out;

    conv_v4<<<dim3(NWQ, 4, Bn), 256, 0, stream>>>(x, kern, out);
}

// Round 5
// 39.877 us; speedup vs baseline: 1.6999x; 1.0139x over previous
//
#include <hip/hip_runtime.h>

// out[b, n*7+c, w] = sum_k x[b, w*3+k-21, c] * kern[n, k]   (n in 0..72)
// out[b, 511,   w] = sum_k x[b, w*3+k-21, 0] * kern[73, k]
// Output (32, 512, 2736) fp32.
//
// R5: same store structure as R4 (lane owns a float4 chunk, wave-row-uniform,
// 1KB contiguous per wave-store). ONE structural change: g merged 4->2 so each
// block stages x once and computes twice the rows (prologue amortized 2x,
// stage traffic halved). LDS per-channel stride-776 layout, 16B-aligned ->
// window = 4x ds_read_b128 + 1x b32, 2-way bank alias only (free).

typedef float f32x4 __attribute__((ext_vector_type(4)));

constexpr int Bn   = 32;
constexpr int Sn   = 8192;
constexpr int Cn   = 7;
constexpr int Kn   = 8;
constexpr int PADn = 21;
constexpr int Wn   = 2736;          // (8192+21-8)/3 + 1
constexpr int OCH  = 512;           // 73*7 + 1
constexpr int NCH  = 684;           // float4 chunks per row
constexpr int CHT  = 64;            // chunks per block tile (256 w)
constexpr int NWQ  = 11;            // ceil(684/64)
constexpr int SAMP = 773;           // samples per tile: (256-1)*3 + 8
constexpr int CSTR = 776;           // per-channel LDS stride (>=773, mult of 4)

__global__ __launch_bounds__(256)
void conv_v5(const float* __restrict__ x, const float* __restrict__ kern,
             float* __restrict__ out) {
    __shared__ float lx[Cn * CSTR];      // 21.7 KB -> 7 blocks/CU

    const int tid = threadIdx.x;
    const int wq  = blockIdx.x;          // 0..10  (w-tile)
    const int gp  = blockIdx.y;          // 0..1   (n-half)
    const int b   = blockIdx.z;          // 0..31

    // ---- stage: dense coalesced global reads -> per-channel LDS rows ----
    const int sbase = wq * 768 - PADn;   // first sample of tile (may be <0)
    const int g0    = sbase * Cn;        // flat float offset in batch
    const float* xb = x + (size_t)b * Sn * Cn;
    for (int i = tid; i < SAMP * Cn; i += 256) {
        int gg = g0 + i;
        float v = (gg >= 0 && gg < Sn * Cn) ? xb[gg] : 0.0f;
        int s = i / 7;                   // magic-mul, cheap
        int c = i - 7 * s;
        lx[c * CSTR + s] = v;
    }
    __syncthreads();

    const int lane  = tid & 63;
    const int r     = __builtin_amdgcn_readfirstlane(tid >> 6);  // wave 0..3
    const int chunk = wq * CHT + lane;
    if (chunk >= NCH) return;            // only wq==10 lanes 44..63

    // n-range for this block-half: gp==0 -> 0..35, gp==1 -> 36..72
    const int n0 = gp ? 36 : 0;
    const int n1 = gp ? 73 : 36;

    float* ob = out + (size_t)b * OCH * Wn + 4 * chunk;
    const int sloc = 12 * lane;          // window start sample (local)

    for (int c = 0; c < Cn; ++c) {
        // 17-sample window, 16B-aligned: 4x b128 + 1x b32
        const float* lr = lx + c * CSTR + sloc;
        float xw[17];
        *reinterpret_cast<f32x4*>(xw + 0)  = *reinterpret_cast<const f32x4*>(lr + 0);
        *reinterpret_cast<f32x4*>(xw + 4)  = *reinterpret_cast<const f32x4*>(lr + 4);
        *reinterpret_cast<f32x4*>(xw + 8)  = *reinterpret_cast<const f32x4*>(lr + 8);
        *reinterpret_cast<f32x4*>(xw + 12) = *reinterpret_cast<const f32x4*>(lr + 12);
        xw[16] = lr[16];

        for (int n = n0 + r; n < n1; n += 4) {   // wave-uniform rows
            const float* kr = kern + n * Kn;
            float a0 = 0.f, a1 = 0.f, a2 = 0.f, a3 = 0.f;
#pragma unroll
            for (int k = 0; k < 8; ++k) {
                float kv = kr[k];
                a0 = fmaf(xw[0 + k], kv, a0);
                a1 = fmaf(xw[3 + k], kv, a1);
                a2 = fmaf(xw[6 + k], kv, a2);
                a3 = fmaf(xw[9 + k], kv, a3);
            }
            f32x4 o = {a0, a1, a2, a3};
            *reinterpret_cast<f32x4*>(ob + (size_t)(n * 7 + c) * Wn) = o;
        }
        if (c == 0 && gp == 1 && r == 3) {       // row 511 (kern 73, ch 0)
            const float* kr = kern + 73 * Kn;
            float a0 = 0.f, a1 = 0.f, a2 = 0.f, a3 = 0.f;
#pragma unroll
            for (int k = 0; k < 8; ++k) {
                float kv = kr[k];
                a0 = fmaf(xw[0 + k], kv, a0);
                a1 = fmaf(xw[3 + k], kv, a1);
                a2 = fmaf(xw[6 + k], kv, a2);
                a3 = fmaf(xw[9 + k], kv, a3);
            }
            f32x4 o = {a0, a1, a2, a3};
            *reinterpret_cast<f32x4*>(ob + (size_t)511 * Wn) = o;
        }
    }
}

extern "C" void kernel_launch(void* const* d_in, const int* in_sizes, int n_in,
                              void* d_out, int out_size, void* d_ws, size_t ws_size,
                              hipStream_t stream) {
    const float* x    = (const float*)d_in[0];
    const float* kern = (const float*)d_in[1];
    float* out        = (float*)d_out;

    conv_v5<<<dim3(NWQ, 2, Bn), 256, 0, stream>>>(x, kern, out);
}